// Round 4
// baseline (70.926 us; speedup 1.0000x reference)
//
#include <hip/hip_runtime.h>

#define B_DIM   1024
#define IN_DIM  1024
#define OUT_DIM 2048
#define NBITS   6
#define NENT    64   // 1 << NBITS

#define OB   256     // o per block (== blockDim.x, o is the lane dim)
#define BB   16      // b per block -> x tile = BB*4KB = 64 KB LDS, 2 blocks/CU

// One fused kernel. o in the lane dim: lut loads, mapping loads, out stores
// all naturally parallel across lanes. Each thread:
//   1. loads ITS lut row (64 floats) global->registers (dense 64KB/block,
//      L2-resident after first ob-pass; no LDS round trip),
//   2. finite-difference transforms it in-register to multilinear coeffs
//      c_S  (out = sum_S c_S * prod_{j in S} x_mp[j]),
//   3. for each of BB batch rows staged in LDS: 6 random-bank LDS gathers
//      (<=2-way expected conflicts ~ free) + 63-FMA Horner binary fold.
// Register budget: v[64] + 2x w[32] (unroll 2) + ~20 misc ~= 150 VGPR,
// under the 256 cap from __launch_bounds__(256,2) -> no scratch spill.
__global__ __launch_bounds__(256, 2) void lut_fused(
    const float* __restrict__ x,
    const float* __restrict__ lut,
    const int*   __restrict__ mapping,
    float*       __restrict__ out)
{
    __shared__ __align__(16) float sx[BB * IN_DIM];   // 64 KB
    const int tid = threadIdx.x;
    const int o0  = blockIdx.x * OB;
    const int b0  = blockIdx.y * BB;
    const int o   = o0 + tid;

    // ---- kick off x tile staging (coalesced float4, 16 per thread) ----
    const float4* xsrc = (const float4*)(x + (size_t)b0 * IN_DIM);
    float4* xdst = (float4*)sx;
#pragma unroll
    for (int i = 0; i < (BB * IN_DIM / 4) / OB; i++) { // 16 iters
        const int f = i * OB + tid;
        xdst[f] = xsrc[f];
    }

    // ---- my lut row: 16 dwordx4 global loads straight to registers ----
    float v[NENT];
    {
        const float4* lr = (const float4*)(lut + (size_t)o * NENT);
#pragma unroll
        for (int q = 0; q < NENT / 4; q++) {
            const float4 t = lr[q];
            v[4 * q + 0] = t.x; v[4 * q + 1] = t.y;
            v[4 * q + 2] = t.z; v[4 * q + 3] = t.w;
        }
    }

    // ---- my mapping (6 ints) ----
    int mp[NBITS];
#pragma unroll
    for (int j = 0; j < NBITS; j++) mp[j] = mapping[(size_t)o * NBITS + j];

    // ---- in-register finite-difference transform: per bit j, hi -= lo ----
#pragma unroll
    for (int j = 0; j < NBITS; j++) {
#pragma unroll
        for (int k = 0; k < NENT; k++) {
            if ((k >> j) & 1) v[k] -= v[k ^ (1 << j)];
        }
    }

    __syncthreads();   // x tile ready

    // ---- main loop: 6 LDS gathers + 63-FMA Horner per (b,o) ----
#pragma unroll 2
    for (int bi = 0; bi < BB; bi++) {
        const float* xr = &sx[bi * IN_DIM];            // bi uniform per iter
        float xv[NBITS];
#pragma unroll
        for (int j = 0; j < NBITS; j++) xv[j] = xr[mp[j]];

        float w[NENT / 2];
        {
            const float xj = xv[0];
#pragma unroll
            for (int m = 0; m < NENT / 2; m++)
                w[m] = fmaf(xj, v[2 * m + 1], v[2 * m]);
        }
#pragma unroll
        for (int j = 1; j < NBITS; j++) {
            const float xj = xv[j];
#pragma unroll
            for (int m = 0; m < (NENT >> (j + 1)); m++)
                w[m] = fmaf(xj, w[2 * m + 1], w[2 * m]);
        }
        out[(size_t)(b0 + bi) * OUT_DIM + o] = w[0];
    }
}

extern "C" void kernel_launch(void* const* d_in, const int* in_sizes, int n_in,
                              void* d_out, int out_size, void* d_ws, size_t ws_size,
                              hipStream_t stream) {
    const float* x       = (const float*)d_in[0];
    const float* lut     = (const float*)d_in[1];
    const int*   mapping = (const int*)d_in[2];
    float*       out     = (float*)d_out;
    (void)d_ws; (void)ws_size;

    const dim3 grid(OUT_DIM / OB, B_DIM / BB);   // 8 x 64 = 512 blocks, 2/CU
    lut_fused<<<grid, 256, 0, stream>>>(x, lut, mapping, out);
}